// Round 1
// baseline (1126.340 us; speedup 1.0000x reference)
//
#include <hip/hip_runtime.h>
#include <hip/hip_bf16.h>
#include <math.h>

// Shapes
#define N_TRAIN 4096
#define N_FEAT  64
#define N_HID   256
#define ENC     256
#define N_ANTES 2048
#define ATT_H   256
#define MAX_LEN 16

typedef unsigned int u32;

__device__ __forceinline__ float fsig(float x)  { return 1.f / (1.f + __expf(-x)); }
__device__ __forceinline__ float ftanh(float x) { return 2.f / (1.f + __expf(-2.f * x)) - 1.f; }

// ---------------------------------------------------------------------------
// Tiled GEMM: C[m,n] = act(bias[n] + sum_k A[m,k] * B[n,k]); 64x64x16 tiles.
// ---------------------------------------------------------------------------
template <bool RELU>
__global__ __launch_bounds__(256) void gemm_abT(
    const float* __restrict__ A, const float* __restrict__ B,
    const float* __restrict__ bias, float* __restrict__ C,
    int M, int N, int K, int lda, int ldb, int ldc)
{
    __shared__ __align__(16) float As[16][68];
    __shared__ __align__(16) float Bs[16][68];
    const int tid = threadIdx.x;
    const int m0 = blockIdx.x * 64, n0 = blockIdx.y * 64;
    const int tx = tid & 15, ty = tid >> 4;
    const int kl = tid & 15, rl = tid >> 4;
    float acc[4][4] = {};

    for (int k0 = 0; k0 < K; k0 += 16) {
        #pragma unroll
        for (int pp = 0; pp < 4; ++pp) {
            int r = rl + pp * 16;
            As[kl][r] = A[(size_t)(m0 + r) * lda + k0 + kl];
            Bs[kl][r] = B[(size_t)(n0 + r) * ldb + k0 + kl];
        }
        __syncthreads();
        #pragma unroll
        for (int k = 0; k < 16; ++k) {
            float4 av = *(const float4*)&As[k][ty * 4];
            float4 bv = *(const float4*)&Bs[k][tx * 4];
            float a4[4] = {av.x, av.y, av.z, av.w};
            float b4[4] = {bv.x, bv.y, bv.z, bv.w};
            #pragma unroll
            for (int i = 0; i < 4; ++i)
                #pragma unroll
                for (int j = 0; j < 4; ++j)
                    acc[i][j] = fmaf(a4[i], b4[j], acc[i][j]);
        }
        __syncthreads();
    }
    #pragma unroll
    for (int i = 0; i < 4; ++i) {
        int m = m0 + ty * 4 + i;
        #pragma unroll
        for (int j = 0; j < 4; ++j) {
            int n = n0 + tx * 4 + j;
            float v = acc[i][j] + bias[n];
            if (RELU) v = fmaxf(v, 0.f);
            C[(size_t)m * ldc + n] = v;
        }
    }
}

// ---------------------------------------------------------------------------
// Split-K GEMM, partials to plain buffers (no atomics). Grid (M/64,N/64,4).
// ---------------------------------------------------------------------------
#define KSPLIT 4
__global__ __launch_bounds__(256) void gemm_ab_splitk(
    const float* __restrict__ A, const float* __restrict__ B,
    float* __restrict__ pA, float* __restrict__ pB,
    int M, int N, int K, int lda, int ldb, int ldc)
{
    __shared__ __align__(16) float As[16][68];
    __shared__ __align__(16) float Bs[16][64];
    const int tid = threadIdx.x;
    const int m0 = blockIdx.x * 64, n0 = blockIdx.y * 64;
    const int kchunk = K / KSPLIT;
    const int kbeg = blockIdx.z * kchunk, kend = kbeg + kchunk;
    const int tx = tid & 15, ty = tid >> 4;
    const int kl = tid & 15, rl = tid >> 4;
    const int kb = tid >> 6, nb = tid & 63;
    float acc[4][4] = {};

    for (int k0 = kbeg; k0 < kend; k0 += 16) {
        #pragma unroll
        for (int pp = 0; pp < 4; ++pp) {
            As[kl][rl + pp * 16] = A[(size_t)(m0 + rl + pp * 16) * lda + k0 + kl];
            Bs[kb + pp * 4][nb]  = B[(size_t)(k0 + kb + pp * 4) * ldb + n0 + nb];
        }
        __syncthreads();
        #pragma unroll
        for (int k = 0; k < 16; ++k) {
            float4 av = *(const float4*)&As[k][ty * 4];
            float4 bv = *(const float4*)&Bs[k][tx * 4];
            float a4[4] = {av.x, av.y, av.z, av.w};
            float b4[4] = {bv.x, bv.y, bv.z, bv.w};
            #pragma unroll
            for (int i = 0; i < 4; ++i)
                #pragma unroll
                for (int j = 0; j < 4; ++j)
                    acc[i][j] = fmaf(a4[i], b4[j], acc[i][j]);
        }
        __syncthreads();
    }
    float* Cp = (blockIdx.z < 2) ? (pA + (size_t)blockIdx.z * (ATT_H * N_ANTES))
                                 : (pB + (size_t)(blockIdx.z - 2) * (ATT_H * N_ANTES));
    #pragma unroll
    for (int i = 0; i < 4; ++i)
        #pragma unroll
        for (int j = 0; j < 4; ++j)
            Cp[(size_t)(m0 + ty * 4 + i) * ldc + n0 + tx * 4 + j] = acc[i][j];
}

__global__ __launch_bounds__(256) void k_reduce(
    const float* __restrict__ pA, const float* __restrict__ pB,
    float* __restrict__ preT)
{
    int gid = blockIdx.x * 256 + threadIdx.x;
    const int SZ = ATT_H * N_ANTES;
    preT[gid] = (pA[gid] + pA[gid + SZ]) + (pB[gid] + pB[gid + SZ]);
}

// ---------------------------------------------------------------------------
// rowsum[j] = sum_k w_ih[j, k]
// ---------------------------------------------------------------------------
__global__ __launch_bounds__(256) void k_rowsum(const float* __restrict__ w_ih,
                                                float* __restrict__ rowsum)
{
    __shared__ float red[256];
    const int j = blockIdx.x, tid = threadIdx.x;
    float s = 0.f;
    for (int i = tid; i < N_ANTES; i += 256) s += w_ih[(size_t)j * N_ANTES + i];
    red[tid] = s; __syncthreads();
    for (int off = 128; off > 0; off >>= 1) {
        if (tid < off) red[tid] += red[tid + off];
        __syncthreads();
    }
    if (tid == 0) rowsum[j] = red[0];
}

// ---------------------------------------------------------------------------
// wpkT[k*1024 + j] = w_hh[j*256 + k]   (k-major: coalesced per-k loads)
// ---------------------------------------------------------------------------
__global__ __launch_bounds__(256) void k_packT(const float* __restrict__ w_hh,
                                               float* __restrict__ wpkT)
{
    int gid = blockIdx.x * 256 + threadIdx.x;  // 0..262143
    int j = gid >> 8;
    int k = gid & 255;
    wpkT[(size_t)k * 1024 + j] = w_hh[gid];
}

// ---------------------------------------------------------------------------
// WbT[k*256 + j] = att_w1[j*(N_TRAIN+ENC) + N_TRAIN + k]
// ---------------------------------------------------------------------------
__global__ __launch_bounds__(256) void k_wbT(const float* __restrict__ att_w1,
                                             float* __restrict__ WbT)
{
    int gid = blockIdx.x * 256 + threadIdx.x;  // 0..65535
    int j = gid >> 8, k = gid & 255;
    WbT[(size_t)k * 256 + j] = att_w1[(size_t)j * (N_TRAIN + ENC) + N_TRAIN + k];
}

// ---------------------------------------------------------------------------
// LSTM step, restructured for occupancy: 1024 threads/block, grid 256
// (16 waves/CU = 4/SIMD). Thread tid owns gate-row j = tid (j = g*256+jj).
// Per k: 1 coalesced global load of wpkT[k][j] (4-deep register prefetch,
// NO barrier in the K-loop -> no vmcnt drain) + 4 broadcast ds_read_b128 of
// the h tile + 16 FMAs. Gate exchange via z_lds, fused c/h update.
// ---------------------------------------------------------------------------
#define LROWS 16
#define HSTR 20
__global__ __launch_bounds__(1024, 4) void k_lstm(
    float* __restrict__ h, float* __restrict__ c,
    const float* __restrict__ wpkT, const float* __restrict__ rowsum,
    const float* __restrict__ b_ih, const float* __restrict__ b_hh,
    const float* __restrict__ S, const int* __restrict__ idx_buf, int t,
    float* __restrict__ e_accum_t)
{
    __shared__ __align__(16) float h_lds[256 * HSTR];        // [k][r], 20 KB
    __shared__ float z_lds[LROWS * 1024];                    // [r][j], 64 KB
    __shared__ float red[1024];
    __shared__ float a_lds[LROWS];
    const int tid = threadIdx.x;                             // 0..1023
    const int n0 = blockIdx.x * LROWS;

    if (tid < LROWS) {
        float a = 1.0f;
        if (t > 0) a = S[(size_t)(n0 + tid) * N_ANTES + idx_buf[t - 1]];
        a_lds[tid] = a;
    }
    // stage h tile -> h_lds[k][r] (threads 0..255, col k = tid)
    if (tid < 256) {
        float hreg[LROWS];
        #pragma unroll
        for (int r = 0; r < LROWS; ++r)
            hreg[r] = h[(size_t)(n0 + r) * 256 + tid];
        #pragma unroll
        for (int q = 0; q < 4; ++q)
            *(float4*)&h_lds[tid * HSTR + q * 4] =
                make_float4(hreg[q*4], hreg[q*4+1], hreg[q*4+2], hreg[q*4+3]);
    }

    // 4-deep rotating register prefetch of wpkT (padded +4 k-rows)
    float wbuf[4];
    #pragma unroll
    for (int i = 0; i < 4; ++i) wbuf[i] = wpkT[(size_t)i * 1024 + tid];

    const float rs = rowsum[tid];
    const float bs = b_ih[tid] + b_hh[tid];

    __syncthreads();

    float acc[LROWS];
    #pragma unroll
    for (int r = 0; r < LROWS; ++r) acc[r] = fmaf(a_lds[r], rs, bs);

    for (int k4 = 0; k4 < 256; k4 += 4) {
        #pragma unroll
        for (int u = 0; u < 4; ++u) {
            float w = wbuf[u];
            wbuf[u] = wpkT[(size_t)(k4 + 4 + u) * 1024 + tid];  // pad rows ok
            const float4* hrow = (const float4*)&h_lds[(k4 + u) * HSTR];
            float4 h0 = hrow[0], h1 = hrow[1], h2 = hrow[2], h3 = hrow[3];
            float hk[LROWS] = {h0.x, h0.y, h0.z, h0.w, h1.x, h1.y, h1.z, h1.w,
                               h2.x, h2.y, h2.z, h2.w, h3.x, h3.y, h3.z, h3.w};
            #pragma unroll
            for (int r = 0; r < LROWS; ++r)
                acc[r] = fmaf(w, hk[r], acc[r]);
        }
    }

    // exchange gates: z_lds[r][j]
    #pragma unroll
    for (int r = 0; r < LROWS; ++r) z_lds[r * 1024 + tid] = acc[r];
    __syncthreads();

    // fused gate update: thread handles (rbase, jj), rows rbase*4..rbase*4+3
    const int jj = tid & 255, rbase = tid >> 8;
    float esum = 0.f;
    #pragma unroll
    for (int i = 0; i < 4; ++i) {
        int r = rbase * 4 + i;
        float zi = z_lds[r * 1024 + jj];
        float zf = z_lds[r * 1024 + 256 + jj];
        float zg = z_lds[r * 1024 + 512 + jj];
        float zo = z_lds[r * 1024 + 768 + jj];
        size_t off = (size_t)(n0 + r) * 256 + jj;
        float cn = fsig(zf) * c[off] + fsig(zi) * ftanh(zg);
        float hn = fsig(zo) * ftanh(cn);
        c[off] = cn;
        h[off] = hn;
        esum += hn;
    }
    red[tid] = esum;
    __syncthreads();
    if (tid < 256) {
        float e = (red[tid] + red[tid + 256]) + (red[tid + 512] + red[tid + 768]);
        atomicAdd(&e_accum_t[tid], e);
    }
}

// ---------------------------------------------------------------------------
// Fused attention: scores + log-softmax + argmax in ONE kernel.
// Phase 1 (all 64 blocks): u[j] = att_b1[j] + sum_k e_t[k]*WbT[k,j]
//   (redundant per block, coalesced); scores[p] for this block's 32 cols.
// Phase 2 (last block only, via device-scope counter): re-read all 2048
//   scores after an acquire fence, log-softmax + argmax, write out_t/idx_t,
//   self-reset counter for the next step (stream order makes this safe).
// ---------------------------------------------------------------------------
__global__ __launch_bounds__(256) void k_att(
    const float* __restrict__ preT, const float* __restrict__ e_accum_t,
    const float* __restrict__ WbT, const float* __restrict__ att_b1,
    const float* __restrict__ att_w2, const float* __restrict__ att_b2,
    float* __restrict__ scores, float* __restrict__ out_t,
    int* __restrict__ idx_t, int* __restrict__ cnt)
{
    __shared__ float e_lds[256];
    __shared__ float u[256];
    __shared__ float w2s[256];
    __shared__ float red[256];
    const int tid = threadIdx.x;
    e_lds[tid] = e_accum_t[tid] * (1.f / (float)N_TRAIN);
    w2s[tid] = att_w2[tid];
    __syncthreads();

    float uacc = att_b1[tid];
    for (int k = 0; k < 256; ++k)
        uacc = fmaf(e_lds[k], WbT[(size_t)k * 256 + tid], uacc);
    u[tid] = uacc;
    __syncthreads();

    const int pl = tid & 31, jq = tid >> 5;   // 8-way j split
    const int p = blockIdx.x * 32 + pl;
    float sc = 0.f;
    #pragma unroll 4
    for (int j = jq; j < 256; j += 8) {
        float v = preT[(size_t)j * N_ANTES + p] + u[j];
        sc = fmaf(fmaxf(v, 0.f), w2s[j], sc);
    }
    red[tid] = sc;
    __syncthreads();
    if (tid < 32) {
        float s = att_b2[0];
        #pragma unroll
        for (int q = 0; q < 8; ++q) s += red[tid + q * 32];
        scores[blockIdx.x * 32 + tid] = s;
    }

    // ---- last-block handshake (rocPRIM look-back pattern) ----
    __threadfence();            // release: drain/flush this block's score writes
    __syncthreads();
    __shared__ int is_last;
    if (tid == 0)
        is_last = (atomicAdd(cnt, 1) == (int)gridDim.x - 1);
    __syncthreads();
    if (!is_last) return;
    __threadfence();            // acquire: invalidate before reading others' scores

    // ---- phase 2: log-softmax + argmax over 2048 scores (one block) ----
    __shared__ float smax[256];
    __shared__ int   sidx[256];
    __shared__ float ssum[256];

    float sv[8];
    #pragma unroll
    for (int i = 0; i < 8; ++i) sv[i] = scores[tid * 8 + i];

    float lmax = -INFINITY; int lidx = 0;
    #pragma unroll
    for (int i = 0; i < 8; ++i)
        if (sv[i] > lmax) { lmax = sv[i]; lidx = tid * 8 + i; }
    smax[tid] = lmax; sidx[tid] = lidx;
    __syncthreads();
    for (int off = 128; off > 0; off >>= 1) {
        if (tid < off) {
            float ov = smax[tid + off]; int oi = sidx[tid + off];
            if (ov > smax[tid] || (ov == smax[tid] && oi < sidx[tid])) {
                smax[tid] = ov; sidx[tid] = oi;
            }
        }
        __syncthreads();
    }
    const float gmax = smax[0];
    const int gidx = sidx[0];

    float lsum = 0.f;
    #pragma unroll
    for (int i = 0; i < 8; ++i) lsum += __expf(sv[i] - gmax);
    ssum[tid] = lsum;
    __syncthreads();
    for (int off = 128; off > 0; off >>= 1) {
        if (tid < off) ssum[tid] += ssum[tid + off];
        __syncthreads();
    }
    const float lse = gmax + logf(ssum[0]);

    #pragma unroll
    for (int i = 0; i < 8; ++i)
        out_t[tid * 8 + i] = sv[i] - lse;
    if (tid == 0) {
        idx_t[0] = gidx;
        *cnt = 0;               // self-reset for next step (stream-ordered)
    }
}

// ---------------------------------------------------------------------------
extern "C" void kernel_launch(void* const* d_in, const int* in_sizes, int n_in,
                              void* d_out, int out_size, void* d_ws, size_t ws_size,
                              hipStream_t stream)
{
    (void)in_sizes; (void)n_in; (void)out_size; (void)ws_size;
    const float* context = (const float*)d_in[0];
    const float* S       = (const float*)d_in[1];
    const float* enc_w1  = (const float*)d_in[2];
    const float* enc_b1  = (const float*)d_in[3];
    const float* enc_w2  = (const float*)d_in[4];
    const float* enc_b2  = (const float*)d_in[5];
    const float* w_ih    = (const float*)d_in[6];
    const float* w_hh    = (const float*)d_in[7];
    const float* b_ih    = (const float*)d_in[8];
    const float* b_hh    = (const float*)d_in[9];
    const float* att_w1  = (const float*)d_in[10];
    const float* att_b1  = (const float*)d_in[11];
    const float* att_w2  = (const float*)d_in[12];
    const float* att_b2  = (const float*)d_in[13];
    float* out = (float*)d_out;
    float* ws  = (float*)d_ws;

    // ws layout (float offsets)
    float* h      = ws;                        // 1,048,576
    float* c      = ws + 1048576;              // 1,048,576
    float* buf4M  = ws + 2097152;              // hid1, then splitk pA (1,048,576)
    float* preT   = ws + 3145728;              // 524,288
    float* partB  = ws + 3670016;              // splitk pB (1,048,576)
    float* wpkT   = ws + 4718592;              // 262,144 + 4,096 pad
    float* rowsum = ws + 4984832;              // 1,024
    float* e_acc  = ws + 4985856;              // 4,096
    float* scores = ws + 4989952;              // 2,048
    float* WbT    = ws + 4992000;              // 65,536
    int*   idxbuf = (int*)(ws + 5057536);      // 16
    // cnt lives in wpkT's prefetch pad (rows 256..259 are read-garbage only,
    // never written by k_packT and never used as FMA operands)
    int*   cnt    = (int*)(ws + 4980736);

    hipMemsetAsync(c, 0, (size_t)N_TRAIN * ENC * sizeof(float), stream);
    hipMemsetAsync(e_acc, 0, (size_t)MAX_LEN * ENC * sizeof(float), stream);
    hipMemsetAsync(cnt, 0, sizeof(int), stream);

    k_rowsum<<<1024, 256, 0, stream>>>(w_ih, rowsum);
    k_packT<<<1024, 256, 0, stream>>>(w_hh, wpkT);
    k_wbT<<<256, 256, 0, stream>>>(att_w1, WbT);

    // encoder
    float* hid1 = buf4M;
    dim3 g1(N_TRAIN / 64, N_HID / 64);
    gemm_abT<true><<<g1, 256, 0, stream>>>(context, enc_w1, enc_b1, hid1,
                                           N_TRAIN, N_HID, N_FEAT, N_FEAT, N_FEAT, N_HID);
    dim3 g2(N_TRAIN / 64, ENC / 64);
    gemm_abT<false><<<g2, 256, 0, stream>>>(hid1, enc_w2, enc_b2, h,
                                            N_TRAIN, ENC, N_HID, N_HID, N_HID, ENC);
    // preT = Wa @ S (split-K partials; buf4M reused after gemm #2 read hid1)
    dim3 g3(ATT_H / 64, N_ANTES / 64, KSPLIT);
    gemm_ab_splitk<<<g3, 256, 0, stream>>>(att_w1, S, buf4M, partB,
                                           ATT_H, N_ANTES, N_TRAIN,
                                           N_TRAIN + ENC, N_ANTES, N_ANTES);
    k_reduce<<<(ATT_H * N_ANTES) / 256, 256, 0, stream>>>(buf4M, partB, preT);

    for (int t = 0; t < MAX_LEN; ++t) {
        k_lstm<<<N_TRAIN / LROWS, 1024, 0, stream>>>(h, c, wpkT, rowsum, b_ih,
                                                     b_hh, S, idxbuf, t,
                                                     e_acc + t * 256);
        k_att<<<N_ANTES / 32, 256, 0, stream>>>(preT, e_acc + t * 256, WbT,
                                                att_b1, att_w2, att_b2, scores,
                                                out + t * N_ANTES, idxbuf + t, cnt);
    }
}

// Round 2
// 1074.759 us; speedup vs baseline: 1.0480x; 1.0480x over previous
//
#include <hip/hip_runtime.h>
#include <hip/hip_bf16.h>
#include <math.h>

// Shapes
#define N_TRAIN 4096
#define N_FEAT  64
#define N_HID   256
#define ENC     256
#define N_ANTES 2048
#define ATT_H   256
#define MAX_LEN 16

typedef unsigned int u32;

__device__ __forceinline__ float fsig(float x)  { return 1.f / (1.f + __expf(-x)); }
__device__ __forceinline__ float ftanh(float x) { return 2.f / (1.f + __expf(-2.f * x)) - 1.f; }

// ---------------------------------------------------------------------------
// Tiled GEMM: C[m,n] = act(bias[n] + sum_k A[m,k] * B[n,k]); 64x64x16 tiles.
// ---------------------------------------------------------------------------
template <bool RELU>
__global__ __launch_bounds__(256) void gemm_abT(
    const float* __restrict__ A, const float* __restrict__ B,
    const float* __restrict__ bias, float* __restrict__ C,
    int M, int N, int K, int lda, int ldb, int ldc)
{
    __shared__ __align__(16) float As[16][68];
    __shared__ __align__(16) float Bs[16][68];
    const int tid = threadIdx.x;
    const int m0 = blockIdx.x * 64, n0 = blockIdx.y * 64;
    const int tx = tid & 15, ty = tid >> 4;
    const int kl = tid & 15, rl = tid >> 4;
    float acc[4][4] = {};

    for (int k0 = 0; k0 < K; k0 += 16) {
        #pragma unroll
        for (int pp = 0; pp < 4; ++pp) {
            int r = rl + pp * 16;
            As[kl][r] = A[(size_t)(m0 + r) * lda + k0 + kl];
            Bs[kl][r] = B[(size_t)(n0 + r) * ldb + k0 + kl];
        }
        __syncthreads();
        #pragma unroll
        for (int k = 0; k < 16; ++k) {
            float4 av = *(const float4*)&As[k][ty * 4];
            float4 bv = *(const float4*)&Bs[k][tx * 4];
            float a4[4] = {av.x, av.y, av.z, av.w};
            float b4[4] = {bv.x, bv.y, bv.z, bv.w};
            #pragma unroll
            for (int i = 0; i < 4; ++i)
                #pragma unroll
                for (int j = 0; j < 4; ++j)
                    acc[i][j] = fmaf(a4[i], b4[j], acc[i][j]);
        }
        __syncthreads();
    }
    #pragma unroll
    for (int i = 0; i < 4; ++i) {
        int m = m0 + ty * 4 + i;
        #pragma unroll
        for (int j = 0; j < 4; ++j) {
            int n = n0 + tx * 4 + j;
            float v = acc[i][j] + bias[n];
            if (RELU) v = fmaxf(v, 0.f);
            C[(size_t)m * ldc + n] = v;
        }
    }
}

// ---------------------------------------------------------------------------
// Split-K GEMM, KSPLIT=8 partials into P0(4)/P1(2)/P2(2). Grid (M/64,N/64,8).
// 1024 blocks -> 4 blocks/CU -> 16 waves/CU (was 2 blocks / 19.8% occ).
// ---------------------------------------------------------------------------
#define KSPLIT 8
__global__ __launch_bounds__(256) void gemm_ab_splitk(
    const float* __restrict__ A, const float* __restrict__ B,
    float* __restrict__ P0, float* __restrict__ P1, float* __restrict__ P2,
    int M, int N, int K, int lda, int ldb, int ldc)
{
    __shared__ __align__(16) float As[16][68];
    __shared__ __align__(16) float Bs[16][64];
    const int tid = threadIdx.x;
    const int m0 = blockIdx.x * 64, n0 = blockIdx.y * 64;
    const int kchunk = K / KSPLIT;
    const int kbeg = blockIdx.z * kchunk, kend = kbeg + kchunk;
    const int tx = tid & 15, ty = tid >> 4;
    const int kl = tid & 15, rl = tid >> 4;
    const int kb = tid >> 6, nb = tid & 63;
    float acc[4][4] = {};

    for (int k0 = kbeg; k0 < kend; k0 += 16) {
        #pragma unroll
        for (int pp = 0; pp < 4; ++pp) {
            As[kl][rl + pp * 16] = A[(size_t)(m0 + rl + pp * 16) * lda + k0 + kl];
            Bs[kb + pp * 4][nb]  = B[(size_t)(k0 + kb + pp * 4) * ldb + n0 + nb];
        }
        __syncthreads();
        #pragma unroll
        for (int k = 0; k < 16; ++k) {
            float4 av = *(const float4*)&As[k][ty * 4];
            float4 bv = *(const float4*)&Bs[k][tx * 4];
            float a4[4] = {av.x, av.y, av.z, av.w};
            float b4[4] = {bv.x, bv.y, bv.z, bv.w};
            #pragma unroll
            for (int i = 0; i < 4; ++i)
                #pragma unroll
                for (int j = 0; j < 4; ++j)
                    acc[i][j] = fmaf(a4[i], b4[j], acc[i][j]);
        }
        __syncthreads();
    }
    const int SZ = ATT_H * N_ANTES;
    const int bz = blockIdx.z;
    float* Cp = (bz < 4) ? P0 + (size_t)bz * SZ
              : (bz < 6) ? P1 + (size_t)(bz - 4) * SZ
                         : P2 + (size_t)(bz - 6) * SZ;
    #pragma unroll
    for (int i = 0; i < 4; ++i)
        #pragma unroll
        for (int j = 0; j < 4; ++j)
            Cp[(size_t)(m0 + ty * 4 + i) * ldc + n0 + tx * 4 + j] = acc[i][j];
}

__global__ __launch_bounds__(256) void k_reduce(
    const float* __restrict__ P0, const float* __restrict__ P1,
    const float* __restrict__ P2, float* __restrict__ preT)
{
    int gid = blockIdx.x * 256 + threadIdx.x;
    const int SZ = ATT_H * N_ANTES;
    float s = ((P0[gid] + P0[gid + SZ]) + (P0[gid + 2 * SZ] + P0[gid + 3 * SZ]))
            + ((P1[gid] + P1[gid + SZ]) + (P2[gid] + P2[gid + SZ]));
    preT[gid] = s;
}

// ---------------------------------------------------------------------------
// rowsum[j] = sum_k w_ih[j, k]
// ---------------------------------------------------------------------------
__global__ __launch_bounds__(256) void k_rowsum(const float* __restrict__ w_ih,
                                                float* __restrict__ rowsum)
{
    __shared__ float red[256];
    const int j = blockIdx.x, tid = threadIdx.x;
    float s = 0.f;
    for (int i = tid; i < N_ANTES; i += 256) s += w_ih[(size_t)j * N_ANTES + i];
    red[tid] = s; __syncthreads();
    for (int off = 128; off > 0; off >>= 1) {
        if (tid < off) red[tid] += red[tid + off];
        __syncthreads();
    }
    if (tid == 0) rowsum[j] = red[0];
}

// ---------------------------------------------------------------------------
// wpkT[k*1024 + j] = w_hh[j*256 + k]   (k-major: coalesced per-k loads)
// ---------------------------------------------------------------------------
__global__ __launch_bounds__(256) void k_packT(const float* __restrict__ w_hh,
                                               float* __restrict__ wpkT)
{
    int gid = blockIdx.x * 256 + threadIdx.x;  // 0..262143
    int j = gid >> 8;
    int k = gid & 255;
    wpkT[(size_t)k * 1024 + j] = w_hh[gid];
}

// ---------------------------------------------------------------------------
// WbT[k*256 + j] = att_w1[j*(N_TRAIN+ENC) + N_TRAIN + k]
// ---------------------------------------------------------------------------
__global__ __launch_bounds__(256) void k_wbT(const float* __restrict__ att_w1,
                                             float* __restrict__ WbT)
{
    int gid = blockIdx.x * 256 + threadIdx.x;  // 0..65535
    int j = gid >> 8, k = gid & 255;
    WbT[(size_t)k * 256 + j] = att_w1[(size_t)j * (N_TRAIN + ENC) + N_TRAIN + k];
}

// ---------------------------------------------------------------------------
// hT[j*4096 + m] = h[m*256 + j]; 64x64 tiles via LDS. Grid (64, 4).
// ---------------------------------------------------------------------------
__global__ __launch_bounds__(256) void k_packHT(const float* __restrict__ h,
                                                float* __restrict__ hT)
{
    __shared__ float tile[64][65];
    const int tid = threadIdx.x;
    const int m0 = blockIdx.x * 64;
    const int j0 = blockIdx.y * 64;
    const int tc = tid & 63, tr = tid >> 6;
    #pragma unroll
    for (int q = 0; q < 16; ++q)
        tile[tr + q * 4][tc] = h[(size_t)(m0 + tr + q * 4) * 256 + j0 + tc];
    __syncthreads();
    #pragma unroll
    for (int q = 0; q < 16; ++q)
        hT[(size_t)(j0 + tr + q * 4) * 4096 + m0 + tc] = tile[tc][tr + q * 4];
}

// ---------------------------------------------------------------------------
// LSTM step, scalar-h version. 1024 threads/block, grid 256 (1 block/CU).
// h lives transposed in global: hT[k][row] ([256][4096]). Per k, the 16 h
// values a wave needs are wave-uniform -> uniform-address loads compile to
// s_load_dwordx16 (64 B/wave/k through the scalar cache), freeing the LDS
// pipe and the staging barrier entirely. 4-k-deep rotating SGPR prefetch
// (hbuf) + 4-deep VGPR prefetch of w (wbuf). K-loop is pure v_fmac v,s,v.
// Epilogue: z exchange via z_lds, fused gate update, writes hT (transposed)
// + c, block e-contribution via atomicAdd.
// ---------------------------------------------------------------------------
#define LROWS 16
__global__ __launch_bounds__(1024, 4) void k_lstm(
    const float* __restrict__ hT_r, float* __restrict__ hT_w,
    float* __restrict__ c,
    const float* __restrict__ wpkT, const float* __restrict__ rowsum,
    const float* __restrict__ b_ih, const float* __restrict__ b_hh,
    const float* __restrict__ S, const int* __restrict__ idx_buf, int t,
    float* __restrict__ e_accum_t)
{
    __shared__ float z_lds[LROWS * 1024];                    // 64 KB
    __shared__ float red[1024];
    const int tid = threadIdx.x;                             // 0..1023
    const int n0 = blockIdx.x * LROWS;

    // uniform (scalar) loads of a[r] = S[n0+r][idx_{t-1}] (1.0 at t=0)
    float a[LROWS];
    if (t > 0) {
        const int idxp = idx_buf[t - 1];
        const float* Sc = S + idxp;
        #pragma unroll
        for (int r = 0; r < LROWS; ++r)
            a[r] = Sc[(size_t)(n0 + r) * N_ANTES];
    } else {
        #pragma unroll
        for (int r = 0; r < LROWS; ++r) a[r] = 1.f;
    }

    // 4-deep rotating prefetch: w (VGPR, per-lane) and h (SGPR, wave-uniform)
    float wbuf[4];
    #pragma unroll
    for (int i = 0; i < 4; ++i) wbuf[i] = wpkT[(size_t)i * 1024 + tid];

    const float* hTb = hT_r + n0;                            // uniform base
    float hbuf[4][LROWS];
    #pragma unroll
    for (int u = 0; u < 4; ++u)
        #pragma unroll
        for (int r = 0; r < LROWS; ++r)
            hbuf[u][r] = hTb[(size_t)u * 4096 + r];

    const float rs = rowsum[tid];
    const float bs = b_ih[tid] + b_hh[tid];

    float acc[LROWS];
    #pragma unroll
    for (int r = 0; r < LROWS; ++r) acc[r] = fmaf(a[r], rs, bs);

    for (int k4 = 0; k4 < 256; k4 += 4) {
        #pragma unroll
        for (int u = 0; u < 4; ++u) {
            float w = wbuf[u];
            wbuf[u] = wpkT[(size_t)(k4 + u + 4) * 1024 + tid];   // pad rows ok
            float hk[LROWS];
            #pragma unroll
            for (int r = 0; r < LROWS; ++r) hk[r] = hbuf[u][r];
            #pragma unroll
            for (int r = 0; r < LROWS; ++r)                      // prefetch k+4
                hbuf[u][r] = hTb[(size_t)(k4 + u + 4) * 4096 + r]; // pad ok
            #pragma unroll
            for (int r = 0; r < LROWS; ++r)
                acc[r] = fmaf(w, hk[r], acc[r]);
        }
    }

    // exchange gates: z_lds[r][j]
    #pragma unroll
    for (int r = 0; r < LROWS; ++r) z_lds[r * 1024 + tid] = acc[r];
    __syncthreads();

    // fused gate update: thread handles (rbase, jj), rows rbase*4..rbase*4+3
    const int jj = tid & 255, rbase = tid >> 8;
    float esum = 0.f;
    float hn4[4];
    #pragma unroll
    for (int i = 0; i < 4; ++i) {
        int r = rbase * 4 + i;
        float zi = z_lds[r * 1024 + jj];
        float zf = z_lds[r * 1024 + 256 + jj];
        float zg = z_lds[r * 1024 + 512 + jj];
        float zo = z_lds[r * 1024 + 768 + jj];
        size_t off = (size_t)(n0 + r) * 256 + jj;
        float cn = fsig(zf) * c[off] + fsig(zi) * ftanh(zg);
        float hn = fsig(zo) * ftanh(cn);
        c[off] = cn;
        hn4[i] = hn;
        esum += hn;
    }
    // transposed h write: 4 contiguous floats of hT[jj][n0+rbase*4 ..]
    *(float4*)&hT_w[(size_t)jj * 4096 + n0 + rbase * 4] =
        make_float4(hn4[0], hn4[1], hn4[2], hn4[3]);
    red[tid] = esum;
    __syncthreads();
    if (tid < 256) {
        float e = (red[tid] + red[tid + 256]) + (red[tid + 512] + red[tid + 768]);
        atomicAdd(&e_accum_t[tid], e);
    }
}

// ---------------------------------------------------------------------------
// Fused attention: scores + log-softmax + argmax in ONE kernel (last-block).
// ---------------------------------------------------------------------------
__global__ __launch_bounds__(256) void k_att(
    const float* __restrict__ preT, const float* __restrict__ e_accum_t,
    const float* __restrict__ WbT, const float* __restrict__ att_b1,
    const float* __restrict__ att_w2, const float* __restrict__ att_b2,
    float* __restrict__ scores, float* __restrict__ out_t,
    int* __restrict__ idx_t, int* __restrict__ cnt)
{
    __shared__ float e_lds[256];
    __shared__ float u[256];
    __shared__ float w2s[256];
    __shared__ float red[256];
    const int tid = threadIdx.x;
    e_lds[tid] = e_accum_t[tid] * (1.f / (float)N_TRAIN);
    w2s[tid] = att_w2[tid];
    __syncthreads();

    float uacc = att_b1[tid];
    for (int k = 0; k < 256; ++k)
        uacc = fmaf(e_lds[k], WbT[(size_t)k * 256 + tid], uacc);
    u[tid] = uacc;
    __syncthreads();

    const int pl = tid & 31, jq = tid >> 5;   // 8-way j split
    const int p = blockIdx.x * 32 + pl;
    float sc = 0.f;
    #pragma unroll 4
    for (int j = jq; j < 256; j += 8) {
        float v = preT[(size_t)j * N_ANTES + p] + u[j];
        sc = fmaf(fmaxf(v, 0.f), w2s[j], sc);
    }
    red[tid] = sc;
    __syncthreads();
    if (tid < 32) {
        float s = att_b2[0];
        #pragma unroll
        for (int q = 0; q < 8; ++q) s += red[tid + q * 32];
        scores[blockIdx.x * 32 + tid] = s;
    }

    // ---- last-block handshake ----
    __threadfence();
    __syncthreads();
    __shared__ int is_last;
    if (tid == 0)
        is_last = (atomicAdd(cnt, 1) == (int)gridDim.x - 1);
    __syncthreads();
    if (!is_last) return;
    __threadfence();

    // ---- phase 2: log-softmax + argmax over 2048 scores (one block) ----
    __shared__ float smax[256];
    __shared__ int   sidx[256];
    __shared__ float ssum[256];

    float sv[8];
    #pragma unroll
    for (int i = 0; i < 8; ++i) sv[i] = scores[tid * 8 + i];

    float lmax = -INFINITY; int lidx = 0;
    #pragma unroll
    for (int i = 0; i < 8; ++i)
        if (sv[i] > lmax) { lmax = sv[i]; lidx = tid * 8 + i; }
    smax[tid] = lmax; sidx[tid] = lidx;
    __syncthreads();
    for (int off = 128; off > 0; off >>= 1) {
        if (tid < off) {
            float ov = smax[tid + off]; int oi = sidx[tid + off];
            if (ov > smax[tid] || (ov == smax[tid] && oi < sidx[tid])) {
                smax[tid] = ov; sidx[tid] = oi;
            }
        }
        __syncthreads();
    }
    const float gmax = smax[0];
    const int gidx = sidx[0];

    float lsum = 0.f;
    #pragma unroll
    for (int i = 0; i < 8; ++i) lsum += __expf(sv[i] - gmax);
    ssum[tid] = lsum;
    __syncthreads();
    for (int off = 128; off > 0; off >>= 1) {
        if (tid < off) ssum[tid] += ssum[tid + off];
        __syncthreads();
    }
    const float lse = gmax + logf(ssum[0]);

    #pragma unroll
    for (int i = 0; i < 8; ++i)
        out_t[tid * 8 + i] = sv[i] - lse;
    if (tid == 0) {
        idx_t[0] = gidx;
        *cnt = 0;
    }
}

// ---------------------------------------------------------------------------
extern "C" void kernel_launch(void* const* d_in, const int* in_sizes, int n_in,
                              void* d_out, int out_size, void* d_ws, size_t ws_size,
                              hipStream_t stream)
{
    (void)in_sizes; (void)n_in; (void)out_size; (void)ws_size;
    const float* context = (const float*)d_in[0];
    const float* S       = (const float*)d_in[1];
    const float* enc_w1  = (const float*)d_in[2];
    const float* enc_b1  = (const float*)d_in[3];
    const float* enc_w2  = (const float*)d_in[4];
    const float* enc_b2  = (const float*)d_in[5];
    const float* w_ih    = (const float*)d_in[6];
    const float* w_hh    = (const float*)d_in[7];
    const float* b_ih    = (const float*)d_in[8];
    const float* b_hh    = (const float*)d_in[9];
    const float* att_w1  = (const float*)d_in[10];
    const float* att_b1  = (const float*)d_in[11];
    const float* att_w2  = (const float*)d_in[12];
    const float* att_b2  = (const float*)d_in[13];
    float* out = (float*)d_out;
    float* ws  = (float*)d_ws;

    // ws layout (float offsets) — unchanged footprint
    float* h      = ws;                        // 1,048,576 (splitk P0 first)
    float* c      = ws + 1048576;              // 1,048,576 (part of P0)
    float* buf4M  = ws + 2097152;              // splitk P1, then hid1
    float* preT   = ws + 3145728;              // 524,288
    float* partB  = ws + 3670016;              // splitk P2, then hT
    float* wpkT   = ws + 4718592;              // 262,144 + 4,096 pad
    float* rowsum = ws + 4984832;              // 1,024
    float* e_acc  = ws + 4985856;              // 4,096
    float* scores = ws + 4989952;              // 2,048
    float* WbT    = ws + 4992000;              // 65,536
    int*   idxbuf = (int*)(ws + 5057536);      // 16
    int*   cnt    = (int*)(ws + 4980736);      // in wpkT prefetch pad
    float* hT     = partB;                     // [256][4096]; +pad reads spill
                                               // into wpkT region (allocated)

    k_rowsum<<<1024, 256, 0, stream>>>(w_ih, rowsum);
    k_packT<<<1024, 256, 0, stream>>>(w_hh, wpkT);
    k_wbT<<<256, 256, 0, stream>>>(att_w1, WbT);

    // preT = Wa @ S first: its 8 partials (4 M floats) borrow h,c,buf4M,partB
    dim3 g3(ATT_H / 64, N_ANTES / 64, KSPLIT);
    gemm_ab_splitk<<<g3, 256, 0, stream>>>(att_w1, S, ws /*h+c = P0 x4*/,
                                           buf4M /*P1 x2*/, partB /*P2 x2*/,
                                           ATT_H, N_ANTES, N_TRAIN,
                                           N_TRAIN + ENC, N_ANTES, N_ANTES);
    k_reduce<<<(ATT_H * N_ANTES) / 256, 256, 0, stream>>>(ws, buf4M, partB, preT);

    hipMemsetAsync(c, 0, (size_t)N_TRAIN * ENC * sizeof(float), stream);
    hipMemsetAsync(e_acc, 0, (size_t)MAX_LEN * ENC * sizeof(float), stream);
    hipMemsetAsync(cnt, 0, sizeof(int), stream);

    // encoder
    float* hid1 = buf4M;
    dim3 g1(N_TRAIN / 64, N_HID / 64);
    gemm_abT<true><<<g1, 256, 0, stream>>>(context, enc_w1, enc_b1, hid1,
                                           N_TRAIN, N_HID, N_FEAT, N_FEAT, N_FEAT, N_HID);
    dim3 g2(N_TRAIN / 64, ENC / 64);
    gemm_abT<false><<<g2, 256, 0, stream>>>(hid1, enc_w2, enc_b2, h,
                                            N_TRAIN, ENC, N_HID, N_HID, N_HID, ENC);
    // seed hT = h^T
    dim3 gT(N_TRAIN / 64, ENC / 64);
    k_packHT<<<gT, 256, 0, stream>>>(h, hT);

    for (int t = 0; t < MAX_LEN; ++t) {
        k_lstm<<<N_TRAIN / LROWS, 1024, 0, stream>>>(hT, hT, c, wpkT, rowsum,
                                                     b_ih, b_hh, S, idxbuf, t,
                                                     e_acc + t * 256);
        k_att<<<N_ANTES / 32, 256, 0, stream>>>(preT, e_acc + t * 256, WbT,
                                                att_b1, att_w2, att_b2, scores,
                                                out + t * N_ANTES, idxbuf + t, cnt);
    }
}